// Round 6
// baseline (373.578 us; speedup 1.0000x reference)
//
#include <hip/hip_runtime.h>

// QLSTM recurrence on MI355X — round 8.
// Skeleton = round 7 (4 waves / 4 SIMDs, lane g owns h[g], fused-DPP tree,
// per-wave aq-dot pre-exchange, q-affine folded z-weights, tau/owh split,
// merged-rcp pre-scaled gates, x window filler, unroll x2).
//
// Round-8 change: the per-step cross-wave exchange no longer uses
// s_waitcnt lgkmcnt(0) + s_barrier (measured stall ledger says the sync
// segment is ~300-450 cyc/step). Instead, a producer-flag protocol:
//   writers: ds_write data (lanes 48-63), then ds_write flag=t+1 (lane 63).
//            Same-wave DS ops are processed in order -> flag commits after
//            data.
//   readers: issue ds_read_b128(flags) THEN ds_read_b128(data) back-to-back
//            (FIFO DS pipe: if the earlier-processed flag-read sees t+1, the
//            later-processed data-read is guaranteed fresh), overlap the
//            latency with the x filler, one lgkmcnt(0), check min(flags)==t+1,
//            retry on lag. Common case = ONE LDS round trip, no drain, no
//            barrier.
// Safety: 2-slot double buffer + monotone tags; a wave cannot reach step t+2
// until every wave wrote flag(t+1), so max drift = 1 step and slot reuse is
// race-free. Flags zeroed + __syncthreads() once before the loop. Stale flag
// values are always < tag, so min==tag <=> all fresh. sched_barrier(0) after
// the waitcnt blocks rule-18 hoisting of flag-check/combine above the wait.

#define B_ 256
#define T_ 512
#define F_ 128
#define H_ 256

#define SC1 1.442695041f    // log2(e)
#define SC2 2.885390082f    // 2*log2(e)
#define ISC2 0.3465735903f  // 1/SC2

typedef float f4v __attribute__((ext_vector_type(4)));
typedef int   i4v __attribute__((ext_vector_type(4)));

__device__ __forceinline__ float rcp_f(float x)  { return __builtin_amdgcn_rcpf(x); }
__device__ __forceinline__ float exp2_f(float x) { return __builtin_amdgcn_exp2f(x); }

__device__ __forceinline__ float rl(float v, int lane) {
    return __int_as_float(__builtin_amdgcn_readlane(__float_as_int(v), lane));
}

__device__ __forceinline__ int imin2(int a, int b) { return a < b ? a : b; }

// Fused 64-lane sum of 4 independent values; results valid at lanes 48-63.
// 6 levels x 4 interleaved chains: DPP consumer >=4 instrs from producer.
__device__ __forceinline__ void tree4(float& p0, float& p1, float& p2, float& p3) {
    asm volatile(
        "s_nop 1\n\t"
        "v_add_f32_dpp %0, %0, %0 quad_perm:[1,0,3,2] row_mask:0xf bank_mask:0xf\n\t"
        "v_add_f32_dpp %1, %1, %1 quad_perm:[1,0,3,2] row_mask:0xf bank_mask:0xf\n\t"
        "v_add_f32_dpp %2, %2, %2 quad_perm:[1,0,3,2] row_mask:0xf bank_mask:0xf\n\t"
        "v_add_f32_dpp %3, %3, %3 quad_perm:[1,0,3,2] row_mask:0xf bank_mask:0xf\n\t"
        "v_add_f32_dpp %0, %0, %0 quad_perm:[2,3,0,1] row_mask:0xf bank_mask:0xf\n\t"
        "v_add_f32_dpp %1, %1, %1 quad_perm:[2,3,0,1] row_mask:0xf bank_mask:0xf\n\t"
        "v_add_f32_dpp %2, %2, %2 quad_perm:[2,3,0,1] row_mask:0xf bank_mask:0xf\n\t"
        "v_add_f32_dpp %3, %3, %3 quad_perm:[2,3,0,1] row_mask:0xf bank_mask:0xf\n\t"
        "v_add_f32_dpp %0, %0, %0 row_half_mirror row_mask:0xf bank_mask:0xf\n\t"
        "v_add_f32_dpp %1, %1, %1 row_half_mirror row_mask:0xf bank_mask:0xf\n\t"
        "v_add_f32_dpp %2, %2, %2 row_half_mirror row_mask:0xf bank_mask:0xf\n\t"
        "v_add_f32_dpp %3, %3, %3 row_half_mirror row_mask:0xf bank_mask:0xf\n\t"
        "v_add_f32_dpp %0, %0, %0 row_mirror row_mask:0xf bank_mask:0xf\n\t"
        "v_add_f32_dpp %1, %1, %1 row_mirror row_mask:0xf bank_mask:0xf\n\t"
        "v_add_f32_dpp %2, %2, %2 row_mirror row_mask:0xf bank_mask:0xf\n\t"
        "v_add_f32_dpp %3, %3, %3 row_mirror row_mask:0xf bank_mask:0xf\n\t"
        "v_add_f32_dpp %0, %0, %0 row_bcast:15 row_mask:0xf bank_mask:0xf\n\t"
        "v_add_f32_dpp %1, %1, %1 row_bcast:15 row_mask:0xf bank_mask:0xf\n\t"
        "v_add_f32_dpp %2, %2, %2 row_bcast:15 row_mask:0xf bank_mask:0xf\n\t"
        "v_add_f32_dpp %3, %3, %3 row_bcast:15 row_mask:0xf bank_mask:0xf\n\t"
        "v_add_f32_dpp %0, %0, %0 row_bcast:31 row_mask:0xf bank_mask:0xf\n\t"
        "v_add_f32_dpp %1, %1, %1 row_bcast:31 row_mask:0xf bank_mask:0xf\n\t"
        "v_add_f32_dpp %2, %2, %2 row_bcast:31 row_mask:0xf bank_mask:0xf\n\t"
        "v_add_f32_dpp %3, %3, %3 row_bcast:31 row_mask:0xf bank_mask:0xf"
        : "+v"(p0), "+v"(p1), "+v"(p2), "+v"(p3));
}

__global__ __launch_bounds__(256, 1) void qlstm_kernel(
    const float* __restrict__ x,      // [B,T,F]
    const float* __restrict__ W_in,   // [H+F, 4] (row = float4)
    const float* __restrict__ b_in,   // [4]
    const float* __restrict__ Wq,     // [4,4,4]
    const float* __restrict__ bq,     // [4,4]
    const float* __restrict__ W_out,  // [4,H]
    const float* __restrict__ b_out,  // [H]
    float* __restrict__ out)          // [B*T*H] ++ [B*H] ++ [B*H]
{
    const int b = blockIdx.x;
    const int g = threadIdx.x;   // 0..255 — my h index
    const int w = g >> 6;        // wave 0..3
    const int l = g & 63;

    __shared__ __align__(16) float partA[2][16][4];  // [slot][m][wave]
    __shared__ __align__(16) int   flagsA[2][4];     // [slot][wave]

    if (g < 8) ((int*)flagsA)[g] = 0;

    const float4* Win4 = (const float4*)W_in;

    float4 t4 = Win4[g];
    float wh[4] = {t4.x, t4.y, t4.z, t4.w};

    const bool has_x = (w < 2);
    float wx[4] = {0.f, 0.f, 0.f, 0.f};
    if (has_x) {
        float4 u4 = Win4[H_ + g];
        wx[0] = u4.x; wx[1] = u4.y; wx[2] = u4.z; wx[3] = u4.w;
    }

    // z' weights with the per-gate scale sk and the q-affine folded in:
    //   z'[k] = bo2[k] + sum_r q'[k4+r] * wo2[k][r],  q' = rcp(1+exp2(aq))
    const float sk[4] = {-SC1, -SC1, SC2, -SC1};
    float wo2[4][4];
    float bo2[4];
    {
        const float bo = b_out[g];
        float wos[4];
        float wsum = 0.f;
#pragma unroll
        for (int r = 0; r < 4; ++r) { wos[r] = W_out[r * H_ + g]; wsum += wos[r]; }
#pragma unroll
        for (int k = 0; k < 4; ++k) {
            bo2[k] = sk[k] * (bo + wsum);
#pragma unroll
            for (int r = 0; r < 4; ++r) wo2[k][r] = -2.0f * sk[k] * wos[r];
        }
    }

    float bin[4];
#pragma unroll
    for (int q = 0; q < 4; ++q) bin[q] = b_in[q];

    // Lane-distributed q-block (pre-scaled by SC2, b_in folded).
    const int m = l & 15, qk = m >> 2, qr = m & 3;
    float wql[4];
#pragma unroll
    for (int s = 0; s < 4; ++s) wql[s] = Wq[qk * 16 + s * 4 + qr];
    float bql = bq[qk * 4 + qr];
#pragma unroll
    for (int s = 0; s < 4; ++s) bql = fmaf(bin[s], wql[s], bql);
    bql *= SC2;
#pragma unroll
    for (int s = 0; s < 4; ++s) wql[s] *= SC2;
    const float bqlw = (w == 0) ? bql : 0.0f;   // bias added by wave 0 only

    // LDS byte addresses (32-bit), both slots precomputed.
    const unsigned daddr0 = (unsigned)(unsigned long long)&partA[0][m][0];
    const unsigned daddr1 = (unsigned)(unsigned long long)&partA[1][m][0];
    const unsigned faddr0 = (unsigned)(unsigned long long)&flagsA[0][0];
    const unsigned faddr1 = (unsigned)(unsigned long long)&flagsA[1][0];
    const unsigned waddr0 = (unsigned)(unsigned long long)&partA[0][m][w];
    const unsigned waddr1 = (unsigned)(unsigned long long)&partA[1][m][w];
    const unsigned fwadd0 = (unsigned)(unsigned long long)&flagsA[0][w];
    const unsigned fwadd1 = (unsigned)(unsigned long long)&flagsA[1][w];

    // Recurrent state: tau = tanh(c), C = SC2*c, owh = o*wh.
    float tau = 0.f, C = 0.f;
    float owh0 = 0.f, owh1 = 0.f, owh2 = 0.f, owh3 = 0.f;

    const float* xp = x + (size_t)b * T_ * F_ + g;
    float xq0 = 0.f, xq1 = 0.f, xq2 = 0.f, xq3 = 0.f;
    float xv1 = 0.f;
    if (has_x) {
        const float xv0 = xp[0];
        xv1 = xp[F_];
        xq0 = xv0 * wx[0]; xq1 = xv0 * wx[1];
        xq2 = xv0 * wx[2]; xq3 = xv0 * wx[3];
    }

    float* outp = out + (size_t)b * T_ * H_ + g;
    float o_last = 0.f;

    __syncthreads();   // flag init visible before first exchange

#define STEP(t_, slot_)                                                        \
    {                                                                          \
        const int tag = (t_) + 1;                                              \
        float p0 = fmaf(tau, owh0, xq0);                                       \
        float p1 = fmaf(tau, owh1, xq1);                                       \
        float p2 = fmaf(tau, owh2, xq2);                                       \
        float p3 = fmaf(tau, owh3, xq3);                                       \
        tree4(p0, p1, p2, p3);                                                 \
        /* per-wave aq contribution; valid at lanes 48-63 (m = l-48) */        \
        float u = fmaf(p0, wql[0], bqlw);                                      \
        const float vv = fmaf(p3, wql[3], p2 * wql[2]);                        \
        u = fmaf(p1, wql[1], u);                                               \
        const float aqw = u + vv;                                              \
        if (l >= 48)                                                           \
            asm volatile("ds_write_b32 %0, %1"                                 \
                         :: "v"((slot_) ? waddr1 : waddr0), "v"(aqw)           \
                         : "memory");                                          \
        if (l == 63)                                                           \
            asm volatile("ds_write_b32 %0, %1"                                 \
                         :: "v"((slot_) ? fwadd1 : fwadd0), "v"(tag)           \
                         : "memory");                                          \
        /* issue flag-read THEN data-read (FIFO order = visibility proof) */   \
        i4v f; f4v a;                                                          \
        asm volatile("ds_read_b128 %0, %2\n\t"                                 \
                     "ds_read_b128 %1, %3"                                     \
                     : "=&v"(f), "=&v"(a)                                      \
                     : "v"((slot_) ? faddr1 : faddr0),                         \
                       "v"((slot_) ? daddr1 : daddr0)                          \
                     : "memory");                                              \
        /* window filler: next step's x products + prefetch (independent) */   \
        if (has_x) {                                                           \
            xq0 = xv1 * wx[0]; xq1 = xv1 * wx[1];                              \
            xq2 = xv1 * wx[2]; xq3 = xv1 * wx[3];                              \
            int tn = (t_) + 2; if (tn >= T_) tn = T_ - 1;                      \
            xv1 = xp[(size_t)tn * F_];                                         \
        }                                                                      \
        asm volatile("s_waitcnt lgkmcnt(0)" ::: "memory");                     \
        __builtin_amdgcn_sched_barrier(0);                                     \
        /* stale flags are strictly < tag (monotone), so min==tag <=> all */   \
        while (imin2(imin2(f.x, f.y), imin2(f.z, f.w)) != tag) {               \
            asm volatile("ds_read_b128 %0, %2\n\t"                             \
                         "ds_read_b128 %1, %3\n\t"                             \
                         "s_waitcnt lgkmcnt(0)"                                \
                         : "=&v"(f), "=&v"(a)                                  \
                         : "v"((slot_) ? faddr1 : faddr0),                     \
                           "v"((slot_) ? daddr1 : daddr0)                      \
                         : "memory");                                          \
            __builtin_amdgcn_sched_barrier(0);                                 \
        }                                                                      \
        const float aq = (a.x + a.y) + (a.z + a.w);                            \
        const float qp = rcp_f(1.0f + exp2_f(aq));   /* q' (affine folded) */  \
        float qs[16];                                                          \
        _Pragma("unroll")                                                      \
        for (int i = 0; i < 16; ++i) qs[i] = rl(qp, i);                        \
        float zp[4];                                                           \
        _Pragma("unroll")                                                      \
        for (int k = 0; k < 4; ++k) {                                          \
            float za = fmaf(qs[k * 4 + 0], wo2[k][0], bo2[k]);                 \
            const float zb = fmaf(qs[k * 4 + 1], wo2[k][1],                    \
                                  qs[k * 4 + 2] * wo2[k][2]);                  \
            za = fmaf(qs[k * 4 + 3], wo2[k][3], za);                           \
            zp[k] = za + zb;                                                   \
        }                                                                      \
        const float e0 = exp2_f(zp[0]);                                        \
        const float e1 = exp2_f(zp[1]);                                        \
        const float E2 = exp2_f(zp[2]);                                        \
        const float e3 = exp2_f(zp[3]);                                        \
        const float num2 = fmaf(SC2, E2, -SC2);                                \
        const float IG2  = num2 * rcp_f((1.0f + e0) * (1.0f + E2));            \
        const float fg   = rcp_f(1.0f + e1);                                   \
        C = fmaf(fg, C, IG2);                                                  \
        /* o-gate path off the C->Ec chain: fills the exp2 latency */          \
        const float o = rcp_f(1.0f + e3);                                      \
        owh0 = o * wh[0]; owh1 = o * wh[1];                                    \
        owh2 = o * wh[2]; owh3 = o * wh[3];                                    \
        const float Ec = exp2_f(C);                                            \
        tau = (Ec - 1.0f) * rcp_f(1.0f + Ec);                                  \
        o_last = o;                                                            \
        outp[(size_t)(t_) * H_] = tau * o;   /* store off-chain */             \
    }

    for (int t = 0; t < T_; t += 2) {
        STEP(t, 0);
        STEP(t + 1, 1);
    }
#undef STEP

    float* hT = out + (size_t)B_ * T_ * H_;
    hT[(size_t)b * H_ + g] = tau * o_last;
    hT[(size_t)B_ * H_ + (size_t)b * H_ + g] = C * ISC2;
}

extern "C" void kernel_launch(void* const* d_in, const int* in_sizes, int n_in,
                              void* d_out, int out_size, void* d_ws, size_t ws_size,
                              hipStream_t stream) {
    const float* x     = (const float*)d_in[0];
    const float* W_in  = (const float*)d_in[1];
    const float* b_in  = (const float*)d_in[2];
    const float* Wq    = (const float*)d_in[3];
    const float* bq    = (const float*)d_in[4];
    const float* W_out = (const float*)d_in[5];
    const float* b_out = (const float*)d_in[6];
    float* out = (float*)d_out;

    qlstm_kernel<<<dim3(B_), dim3(256), 0, stream>>>(
        x, W_in, b_in, Wq, bq, W_out, b_out, out);
}

// Round 7
// 365.139 us; speedup vs baseline: 1.0231x; 1.0231x over previous
//
#include <hip/hip_runtime.h>

// QLSTM recurrence on MI355X — round 9.
// Skeleton = round 7 (best: 233.5 us/dispatch): 4 waves / 4 SIMDs, lane g owns
// h[g], fused-DPP tree, per-wave aq-dot pre-barrier, raw lgkm-only barrier,
// q-affine folded z-weights, tau/owh split, merged-rcp pre-scaled gates,
// x window filler.
// Round-8 lesson (reverted): flag-polling exchange == barrier (238 vs 233) --
// the sync primitive was never the cost; waves are data-lockstepped. The LDS
// round trip (~180 cyc) is the floor for any cross-SIMD exchange.
//
// Round-9: pure issue-trim + spine-priority ordering (in-order wave stream):
//  - z-dots as 4 serial-fma chains (20 -> 16 ops), interleaved.
//  - spine order: k=2 readlanes+dot -> exp2(E2) earliest; k=0, k=1 under its
//    latency; Ec=exp2(C) issued before the k=3/o block (o hides under Ec).
//  - (1+e0)(1+E2) = fma(e0, u2, u2), u2 = 1+E2 (-1 op).
//  - packed pk_add combine of the float4 partials (-1 op).
//  - t-loop unrolled x4.

#define B_ 256
#define T_ 512
#define F_ 128
#define H_ 256

#define SC1 1.442695041f    // log2(e)
#define SC2 2.885390082f    // 2*log2(e)
#define ISC2 0.3465735903f  // 1/SC2

typedef float f2 __attribute__((ext_vector_type(2)));

__device__ __forceinline__ float rcp_f(float x)  { return __builtin_amdgcn_rcpf(x); }
__device__ __forceinline__ float exp2_f(float x) { return __builtin_amdgcn_exp2f(x); }

__device__ __forceinline__ float rl(float v, int lane) {
    return __int_as_float(__builtin_amdgcn_readlane(__float_as_int(v), lane));
}

// Fused 64-lane sum of 4 independent values; results valid at lanes 48-63
// (row 3 accumulates the full sum after row_bcast15 + row_bcast31).
// 6 levels x 4 interleaved chains: DPP consumer >=4 instrs from producer
// (VALU->DPP hazard covered by construction; s_nop 1 guards the entry, since
// the compiler may schedule any of the p-fmas immediately before the asm).
__device__ __forceinline__ void tree4(float& p0, float& p1, float& p2, float& p3) {
    asm volatile(
        "s_nop 1\n\t"
        "v_add_f32_dpp %0, %0, %0 quad_perm:[1,0,3,2] row_mask:0xf bank_mask:0xf\n\t"
        "v_add_f32_dpp %1, %1, %1 quad_perm:[1,0,3,2] row_mask:0xf bank_mask:0xf\n\t"
        "v_add_f32_dpp %2, %2, %2 quad_perm:[1,0,3,2] row_mask:0xf bank_mask:0xf\n\t"
        "v_add_f32_dpp %3, %3, %3 quad_perm:[1,0,3,2] row_mask:0xf bank_mask:0xf\n\t"
        "v_add_f32_dpp %0, %0, %0 quad_perm:[2,3,0,1] row_mask:0xf bank_mask:0xf\n\t"
        "v_add_f32_dpp %1, %1, %1 quad_perm:[2,3,0,1] row_mask:0xf bank_mask:0xf\n\t"
        "v_add_f32_dpp %2, %2, %2 quad_perm:[2,3,0,1] row_mask:0xf bank_mask:0xf\n\t"
        "v_add_f32_dpp %3, %3, %3 quad_perm:[2,3,0,1] row_mask:0xf bank_mask:0xf\n\t"
        "v_add_f32_dpp %0, %0, %0 row_half_mirror row_mask:0xf bank_mask:0xf\n\t"
        "v_add_f32_dpp %1, %1, %1 row_half_mirror row_mask:0xf bank_mask:0xf\n\t"
        "v_add_f32_dpp %2, %2, %2 row_half_mirror row_mask:0xf bank_mask:0xf\n\t"
        "v_add_f32_dpp %3, %3, %3 row_half_mirror row_mask:0xf bank_mask:0xf\n\t"
        "v_add_f32_dpp %0, %0, %0 row_mirror row_mask:0xf bank_mask:0xf\n\t"
        "v_add_f32_dpp %1, %1, %1 row_mirror row_mask:0xf bank_mask:0xf\n\t"
        "v_add_f32_dpp %2, %2, %2 row_mirror row_mask:0xf bank_mask:0xf\n\t"
        "v_add_f32_dpp %3, %3, %3 row_mirror row_mask:0xf bank_mask:0xf\n\t"
        "v_add_f32_dpp %0, %0, %0 row_bcast:15 row_mask:0xf bank_mask:0xf\n\t"
        "v_add_f32_dpp %1, %1, %1 row_bcast:15 row_mask:0xf bank_mask:0xf\n\t"
        "v_add_f32_dpp %2, %2, %2 row_bcast:15 row_mask:0xf bank_mask:0xf\n\t"
        "v_add_f32_dpp %3, %3, %3 row_bcast:15 row_mask:0xf bank_mask:0xf\n\t"
        "v_add_f32_dpp %0, %0, %0 row_bcast:31 row_mask:0xf bank_mask:0xf\n\t"
        "v_add_f32_dpp %1, %1, %1 row_bcast:31 row_mask:0xf bank_mask:0xf\n\t"
        "v_add_f32_dpp %2, %2, %2 row_bcast:31 row_mask:0xf bank_mask:0xf\n\t"
        "v_add_f32_dpp %3, %3, %3 row_bcast:31 row_mask:0xf bank_mask:0xf"
        : "+v"(p0), "+v"(p1), "+v"(p2), "+v"(p3));
}

// LDS-only barrier: drain LDS ops, sync waves. Does NOT drain vmcnt.
__device__ __forceinline__ void lds_barrier() {
    asm volatile("s_waitcnt lgkmcnt(0)\n\ts_barrier" ::: "memory");
}

__global__ __launch_bounds__(256, 1) void qlstm_kernel(
    const float* __restrict__ x,      // [B,T,F]
    const float* __restrict__ W_in,   // [H+F, 4] (row = float4)
    const float* __restrict__ b_in,   // [4]
    const float* __restrict__ Wq,     // [4,4,4]
    const float* __restrict__ bq,     // [4,4]
    const float* __restrict__ W_out,  // [4,H]
    const float* __restrict__ b_out,  // [H]
    float* __restrict__ out)          // [B*T*H] ++ [B*H] ++ [B*H]
{
    const int b = blockIdx.x;
    const int g = threadIdx.x;   // 0..255 — my h index
    const int w = g >> 6;        // wave 0..3
    const int l = g & 63;

    // Exchange: per-wave aq contributions. partA[slot][m][w], 512 B.
    __shared__ __align__(16) float partA[2][16][4];

    const float4* Win4 = (const float4*)W_in;

    float4 t4 = Win4[g];
    float wh[4] = {t4.x, t4.y, t4.z, t4.w};

    const bool has_x = (w < 2);
    float wx[4] = {0.f, 0.f, 0.f, 0.f};
    if (has_x) {
        float4 u4 = Win4[H_ + g];
        wx[0] = u4.x; wx[1] = u4.y; wx[2] = u4.z; wx[3] = u4.w;
    }

    // z' weights with the per-gate scale sk and the q-affine folded in:
    //   z'[k] = bo2[k] + sum_r q'[4k+r] * wo2[k][r],  q' = rcp(1+exp2(aq))
    const float sk[4] = {-SC1, -SC1, SC2, -SC1};
    float wo2[4][4];
    float bo2[4];
    {
        const float bo = b_out[g];
        float wos[4];
        float wsum = 0.f;
#pragma unroll
        for (int r = 0; r < 4; ++r) { wos[r] = W_out[r * H_ + g]; wsum += wos[r]; }
#pragma unroll
        for (int k = 0; k < 4; ++k) {
            bo2[k] = sk[k] * (bo + wsum);
#pragma unroll
            for (int r = 0; r < 4; ++r) wo2[k][r] = -2.0f * sk[k] * wos[r];
        }
    }

    float bin[4];
#pragma unroll
    for (int q = 0; q < 4; ++q) bin[q] = b_in[q];

    // Lane-distributed q-block (pre-scaled by SC2, b_in folded).
    const int m = l & 15, qk = m >> 2, qr = m & 3;
    float wql[4];
#pragma unroll
    for (int s = 0; s < 4; ++s) wql[s] = Wq[qk * 16 + s * 4 + qr];
    float bql = bq[qk * 4 + qr];
#pragma unroll
    for (int s = 0; s < 4; ++s) bql = fmaf(bin[s], wql[s], bql);
    bql *= SC2;
#pragma unroll
    for (int s = 0; s < 4; ++s) wql[s] *= SC2;
    const float bqlw = (w == 0) ? bql : 0.0f;   // bias added by wave 0 only

    // Recurrent state: tau = tanh(c), C = SC2*c, owh = o*wh.
    float tau = 0.f, C = 0.f;
    float owh0 = 0.f, owh1 = 0.f, owh2 = 0.f, owh3 = 0.f;

    const float* xp = x + (size_t)b * T_ * F_ + g;
    float xq0 = 0.f, xq1 = 0.f, xq2 = 0.f, xq3 = 0.f;
    float xv1 = 0.f;
    if (has_x) {
        const float xv0 = xp[0];
        xv1 = xp[F_];
        xq0 = xv0 * wx[0]; xq1 = xv0 * wx[1];
        xq2 = xv0 * wx[2]; xq3 = xv0 * wx[3];
    }

    float* outp = out + (size_t)b * T_ * H_ + g;
    float o_last = 0.f;

#define STEP(t_, slot_)                                                        \
    {                                                                          \
        float p0 = fmaf(tau, owh0, xq0);                                       \
        float p1 = fmaf(tau, owh1, xq1);                                       \
        float p2 = fmaf(tau, owh2, xq2);                                       \
        float p3 = fmaf(tau, owh3, xq3);                                       \
        tree4(p0, p1, p2, p3);                                                 \
        /* per-wave aq contribution; valid at lanes 48-63 (m = l-48) */        \
        float u = fmaf(p0, wql[0], bqlw);                                      \
        const float vv = fmaf(p3, wql[3], p2 * wql[2]);                        \
        u = fmaf(p1, wql[1], u);                                               \
        const float aqw = u + vv;                                              \
        if (l >= 48) partA[slot_][m][w] = aqw;                                 \
        lds_barrier();                                                         \
        const float4 a = *(const float4*)&partA[slot_][m][0];                  \
        /* window filler: next step's x products + prefetch (y-independent) */ \
        if (has_x) {                                                           \
            xq0 = xv1 * wx[0]; xq1 = xv1 * wx[1];                              \
            xq2 = xv1 * wx[2]; xq3 = xv1 * wx[3];                              \
            int tn = (t_) + 2; if (tn >= T_) tn = T_ - 1;                      \
            xv1 = xp[(size_t)tn * F_];                                         \
        }                                                                      \
        /* packed combine: 1 pk_add + 1 add */                                 \
        f2 clo; clo.x = a.x; clo.y = a.y;                                      \
        f2 chi; chi.x = a.z; chi.y = a.w;                                      \
        const f2 cs = clo + chi;                                               \
        const float aq = cs.x + cs.y;                                          \
        const float qp = rcp_f(1.0f + exp2_f(aq));   /* q' (affine folded) */  \
        /* spine-priority: k=2 (g-gate) first -> exp2(E2) issues earliest */   \
        const float qs8  = rl(qp, 8),  qs9  = rl(qp, 9);                       \
        const float qs10 = rl(qp, 10), qs11 = rl(qp, 11);                      \
        const float zp2 = fmaf(qs11, wo2[2][3], fmaf(qs10, wo2[2][2],          \
                          fmaf(qs9,  wo2[2][1], fmaf(qs8,  wo2[2][0],          \
                               bo2[2]))));                                     \
        const float E2 = exp2_f(zp2);                                          \
        const float qs0 = rl(qp, 0), qs1 = rl(qp, 1);                          \
        const float qs2 = rl(qp, 2), qs3 = rl(qp, 3);                          \
        const float zp0 = fmaf(qs3, wo2[0][3], fmaf(qs2, wo2[0][2],            \
                          fmaf(qs1, wo2[0][1], fmaf(qs0, wo2[0][0],            \
                               bo2[0]))));                                     \
        const float e0 = exp2_f(zp0);                                          \
        const float qs4 = rl(qp, 4), qs5 = rl(qp, 5);                          \
        const float qs6 = rl(qp, 6), qs7 = rl(qp, 7);                          \
        const float zp1 = fmaf(qs7, wo2[1][3], fmaf(qs6, wo2[1][2],            \
                          fmaf(qs5, wo2[1][1], fmaf(qs4, wo2[1][0],            \
                               bo2[1]))));                                     \
        const float e1 = exp2_f(zp1);                                          \
        const float u2   = 1.0f + E2;                                          \
        const float den  = fmaf(e0, u2, u2);         /* (1+e0)(1+E2) */        \
        const float num2 = fmaf(SC2, E2, -SC2);      /* SC2*(E2-1) */          \
        const float IG2  = num2 * rcp_f(den);                                  \
        const float fg   = rcp_f(1.0f + e1);                                   \
        C = fmaf(fg, C, IG2);                                                  \
        const float Ec = exp2_f(C);   /* issued before the o-block */          \
        const float qs12 = rl(qp, 12), qs13 = rl(qp, 13);                      \
        const float qs14 = rl(qp, 14), qs15 = rl(qp, 15);                      \
        const float zp3 = fmaf(qs15, wo2[3][3], fmaf(qs14, wo2[3][2],          \
                          fmaf(qs13, wo2[3][1], fmaf(qs12, wo2[3][0],          \
                               bo2[3]))));                                     \
        const float e3 = exp2_f(zp3);                                          \
        const float o  = rcp_f(1.0f + e3);                                     \
        owh0 = o * wh[0]; owh1 = o * wh[1];                                    \
        owh2 = o * wh[2]; owh3 = o * wh[3];                                    \
        tau = (Ec - 1.0f) * rcp_f(1.0f + Ec);                                  \
        o_last = o;                                                            \
        outp[(size_t)(t_) * H_] = tau * o;   /* store off-chain */             \
    }

    for (int t = 0; t < T_; t += 4) {
        STEP(t, 0);
        STEP(t + 1, 1);
        STEP(t + 2, 0);
        STEP(t + 3, 1);
    }
#undef STEP

    float* hT = out + (size_t)B_ * T_ * H_;
    hT[(size_t)b * H_ + g] = tau * o_last;
    hT[(size_t)B_ * H_ + (size_t)b * H_ + g] = C * ISC2;
}

extern "C" void kernel_launch(void* const* d_in, const int* in_sizes, int n_in,
                              void* d_out, int out_size, void* d_ws, size_t ws_size,
                              hipStream_t stream) {
    const float* x     = (const float*)d_in[0];
    const float* W_in  = (const float*)d_in[1];
    const float* b_in  = (const float*)d_in[2];
    const float* Wq    = (const float*)d_in[3];
    const float* bq    = (const float*)d_in[4];
    const float* W_out = (const float*)d_in[5];
    const float* b_out = (const float*)d_in[6];
    float* out = (float*)d_out;

    qlstm_kernel<<<dim3(B_), dim3(256), 0, stream>>>(
        x, W_in, b_in, Wq, bq, W_out, b_out, out);
}